// Round 9
// baseline (450.362 us; speedup 1.0000x reference)
//
#include <hip/hip_runtime.h>

#define B_ 256
#define T_ 1024
#define V_ 5000
#define D_ 100
#define H_ 64
#define C_ 2

typedef float f32x4 __attribute__((ext_vector_type(4)));

#define SCALE_ 2.885390081777927f   // 2*log2(e): exp2(SCALE*x) == e^{2x}

// ---------------------------------------------------------------------------
// Kernel 1: EW[v][h] = 2*log2e*(sum_d E[v][d]*W[d][h] + b[h])   (unchanged)
// ---------------------------------------------------------------------------
__global__ __launch_bounds__(256) void ew_kernel(const float* __restrict__ E,
                                                 const float* __restrict__ W,
                                                 const float* __restrict__ bias,
                                                 float* __restrict__ EW) {
    int idx = blockIdx.x * 256 + threadIdx.x;   // 0 .. V_*H_
    if (idx >= V_ * H_) return;
    int h = idx & (H_ - 1);
    int v = idx >> 6;
    float acc = bias[h];
    const float* Erow = E + v * D_;
    #pragma unroll 4
    for (int d = 0; d < D_; ++d) {
        acc = fmaf(Erow[d], W[d * H_ + h], acc);
    }
    EW[idx] = SCALE_ * acc;
}

// ---------------------------------------------------------------------------
// Kernel 2: RNN. R13: HYBRID broadcast -- split the 64-value h-broadcast
// across BOTH pipes so they overlap:
//   k = 0..31  : grouped v_readlane (VALU pipe; R10 structure, hazard-free)
//   k = 32..63 : 1 ds_write + 8 uniform-address ds_read_b128 (DS pipe;
//                same-address = HW broadcast, conflict-free; single wave +
//                in-order DS pipe => no barrier needed)
// Evidence: R10 grouped-readlane = 587 cyc/step (~430 busy => readlane ~4cyc
// effective); R7 all-LDS = 666 (round-trip fully exposed, no overlap);
// R12 systolic DPP = 743 (serial rotate latency). Hybrid: DS round-trip
// (~220 cyc) runs UNDER the rl-half VALU stream (~190 cyc); VALU issue drops
// to 32 rl + 64 fma + tail ~= 310. sched_group_barrier pins the DS ops at
// step start so the compiler can't sink them behind the VALU stream.
// Kept: reg-pinned SCALE_*U (16 f32x4, single multi-operand pin, R7-proven),
// padded sh_tok, 2-step EW prefetch, tanh = 1 - 2*rcp(exp2(SCALE*x)+1).
// ---------------------------------------------------------------------------
__device__ __forceinline__ float readlane_f(float v, int lane) {
    return __uint_as_float(__builtin_amdgcn_readlane(__float_as_uint(v), lane));
}

__global__ __launch_bounds__(64, 1) void rnn_kernel(const int* __restrict__ tokens,
                                                    const float* __restrict__ EW,
                                                    const float* __restrict__ U,
                                                    const float* __restrict__ Wd,
                                                    const float* __restrict__ bd,
                                                    float* __restrict__ out) {
    const int b = blockIdx.x;     // batch element
    const int j = threadIdx.x;    // 0..63 : hidden unit

    __shared__ int sh_tok[T_ + 2];              // 4 KB + pad (kills tail guard)
    __shared__ alignas(16) float sh_hb[H_];     // h broadcast buffer (256 B)

    // --- (2*log2e)*U column j -> 16 float4 (64 VGPRs). Coalesced. ---
    // uqR: k=0..31 (readlane half), uqL: k=32..63 (LDS half)
    f32x4 uqR[8], uqL[8];
    #pragma unroll
    for (int g = 0; g < 8; ++g) {
        #pragma unroll
        for (int i = 0; i < 4; ++i) {
            uqR[g][i] = SCALE_ * U[(4 * g + i) * H_ + j];
            uqL[g][i] = SCALE_ * U[(32 + 4 * g + i) * H_ + j];
        }
    }
    // SINGLE pin: all 64 values live in VGPRs at once (R7/R9/R10-verified).
    asm volatile("" : "+v"(uqR[0]), "+v"(uqR[1]), "+v"(uqR[2]), "+v"(uqR[3]),
                      "+v"(uqR[4]), "+v"(uqR[5]), "+v"(uqR[6]), "+v"(uqR[7]),
                      "+v"(uqL[0]), "+v"(uqL[1]), "+v"(uqL[2]), "+v"(uqL[3]),
                      "+v"(uqL[4]), "+v"(uqL[5]), "+v"(uqL[6]), "+v"(uqL[7]));

    const int* tok = tokens + b * T_;
    #pragma unroll
    for (int k = 0; k < T_ / H_; ++k) {
        sh_tok[k * H_ + j] = tok[k * H_ + j];    // coalesced
    }
    if (j < 2) sh_tok[T_ + j] = 0;               // pad
    __syncthreads();

    float h = 0.f;
    float pooled = 0.f;

    // 2-step-deep xw prefetch pipeline (covers L2 latency of EW gather)
    int2 tkA = *(const int2*)&sh_tok[0];
    float xw0 = EW[tkA.x * H_ + j];
    float xw1 = EW[tkA.y * H_ + j];

    // readlane group: 8 hazard-free readlanes (distinct SGPRs) then 8 FMAs
    #define RL_GROUP(g)                                                  \
    {                                                                    \
        float s0 = readlane_f(h, 8 * (g) + 0);                           \
        float s1 = readlane_f(h, 8 * (g) + 1);                           \
        float s2 = readlane_f(h, 8 * (g) + 2);                           \
        float s3 = readlane_f(h, 8 * (g) + 3);                           \
        float s4 = readlane_f(h, 8 * (g) + 4);                           \
        float s5 = readlane_f(h, 8 * (g) + 5);                           \
        float s6 = readlane_f(h, 8 * (g) + 6);                           \
        float s7 = readlane_f(h, 8 * (g) + 7);                           \
        asm volatile("" : "+s"(s0), "+s"(s1), "+s"(s2), "+s"(s3),        \
                          "+s"(s4), "+s"(s5), "+s"(s6), "+s"(s7));       \
        a0 = fmaf(s0, uqR[2 * (g) + 0][0], a0);                          \
        a1 = fmaf(s1, uqR[2 * (g) + 0][1], a1);                          \
        a0 = fmaf(s2, uqR[2 * (g) + 0][2], a0);                          \
        a1 = fmaf(s3, uqR[2 * (g) + 0][3], a1);                          \
        a0 = fmaf(s4, uqR[2 * (g) + 1][0], a0);                          \
        a1 = fmaf(s5, uqR[2 * (g) + 1][1], a1);                          \
        a0 = fmaf(s6, uqR[2 * (g) + 1][2], a0);                          \
        a1 = fmaf(s7, uqR[2 * (g) + 1][3], a1);                          \
    }

    // one recurrence step: hybrid broadcast (VALU half + DS half, overlapped)
    #define RNN_STEP(tokv, xwv)                                          \
    {                                                                    \
        sh_hb[j] = h;                                                    \
        f32x4 hv0 = *(const f32x4*)&sh_hb[32];                           \
        f32x4 hv1 = *(const f32x4*)&sh_hb[36];                           \
        f32x4 hv2 = *(const f32x4*)&sh_hb[40];                           \
        f32x4 hv3 = *(const f32x4*)&sh_hb[44];                           \
        f32x4 hv4 = *(const f32x4*)&sh_hb[48];                           \
        f32x4 hv5 = *(const f32x4*)&sh_hb[52];                           \
        f32x4 hv6 = *(const f32x4*)&sh_hb[56];                           \
        f32x4 hv7 = *(const f32x4*)&sh_hb[60];                           \
        __builtin_amdgcn_sched_group_barrier(0x200, 1, 0); /* ds_write */\
        __builtin_amdgcn_sched_group_barrier(0x100, 8, 0); /* ds_read  */\
        float a0 = (xwv), a1 = 0.f, a2 = 0.f, a3 = 0.f;                  \
        RL_GROUP(0) RL_GROUP(1) RL_GROUP(2) RL_GROUP(3)                  \
        a2 = fmaf(hv0[0], uqL[0][0], a2);                                \
        a3 = fmaf(hv0[1], uqL[0][1], a3);                                \
        a2 = fmaf(hv0[2], uqL[0][2], a2);                                \
        a3 = fmaf(hv0[3], uqL[0][3], a3);                                \
        a2 = fmaf(hv1[0], uqL[1][0], a2);                                \
        a3 = fmaf(hv1[1], uqL[1][1], a3);                                \
        a2 = fmaf(hv1[2], uqL[1][2], a2);                                \
        a3 = fmaf(hv1[3], uqL[1][3], a3);                                \
        a2 = fmaf(hv2[0], uqL[2][0], a2);                                \
        a3 = fmaf(hv2[1], uqL[2][1], a3);                                \
        a2 = fmaf(hv2[2], uqL[2][2], a2);                                \
        a3 = fmaf(hv2[3], uqL[2][3], a3);                                \
        a2 = fmaf(hv3[0], uqL[3][0], a2);                                \
        a3 = fmaf(hv3[1], uqL[3][1], a3);                                \
        a2 = fmaf(hv3[2], uqL[3][2], a2);                                \
        a3 = fmaf(hv3[3], uqL[3][3], a3);                                \
        a2 = fmaf(hv4[0], uqL[4][0], a2);                                \
        a3 = fmaf(hv4[1], uqL[4][1], a3);                                \
        a2 = fmaf(hv4[2], uqL[4][2], a2);                                \
        a3 = fmaf(hv4[3], uqL[4][3], a3);                                \
        a2 = fmaf(hv5[0], uqL[5][0], a2);                                \
        a3 = fmaf(hv5[1], uqL[5][1], a3);                                \
        a2 = fmaf(hv5[2], uqL[5][2], a2);                                \
        a3 = fmaf(hv5[3], uqL[5][3], a3);                                \
        a2 = fmaf(hv6[0], uqL[6][0], a2);                                \
        a3 = fmaf(hv6[1], uqL[6][1], a3);                                \
        a2 = fmaf(hv6[2], uqL[6][2], a2);                                \
        a3 = fmaf(hv6[3], uqL[6][3], a3);                                \
        a2 = fmaf(hv7[0], uqL[7][0], a2);                                \
        a3 = fmaf(hv7[1], uqL[7][1], a3);                                \
        a2 = fmaf(hv7[2], uqL[7][2], a2);                                \
        a3 = fmaf(hv7[3], uqL[7][3], a3);                                \
        float x2 = (a0 + a1) + (a2 + a3);                                \
        float ef = __builtin_amdgcn_exp2f(x2);                           \
        float r = __builtin_amdgcn_rcpf(ef + 1.f);                       \
        float hn = fmaf(-2.f, r, 1.f);                                   \
        h = ((tokv) != 0) ? hn : h;                                      \
        pooled += h;                                                     \
    }

    for (int t = 0; t < T_; t += 2) {
        // in-loop pin: any uq spill would force an in-loop reload.
        asm volatile("" :: "v"(uqR[0]), "v"(uqR[1]), "v"(uqR[2]), "v"(uqR[3]),
                           "v"(uqR[4]), "v"(uqR[5]), "v"(uqR[6]), "v"(uqR[7]),
                           "v"(uqL[0]), "v"(uqL[1]), "v"(uqL[2]), "v"(uqL[3]),
                           "v"(uqL[4]), "v"(uqL[5]), "v"(uqL[6]), "v"(uqL[7]));

        // prefetch steps t+2, t+3 (pad makes the tail read safe: EW[0])
        int2 tkB = *(const int2*)&sh_tok[t + 2];
        float xw2 = EW[tkB.x * H_ + j];
        float xw3 = EW[tkB.y * H_ + j];

        RNN_STEP(tkA.x, xw0);
        RNN_STEP(tkA.y, xw1);

        tkA = tkB;
        xw0 = xw2;
        xw1 = xw3;
    }
    #undef RNN_STEP
    #undef RL_GROUP

    // ---- epilogue: pooled mean -> dense(2) -> sigmoid ----
    float p = pooled * (1.0f / (float)T_);
    float v0 = p * Wd[j * C_ + 0];
    float v1 = p * Wd[j * C_ + 1];
    #pragma unroll
    for (int off = 32; off >= 1; off >>= 1) {
        v0 += __shfl_down(v0, off, 64);
        v1 += __shfl_down(v1, off, 64);
    }
    if (j == 0) {
        float l0 = v0 + bd[0];
        float l1 = v1 + bd[1];
        out[b * C_ + 0] = 1.f / (1.f + __expf(-l0));
        out[b * C_ + 1] = 1.f / (1.f + __expf(-l1));
    }
}

// ---------------------------------------------------------------------------
extern "C" void kernel_launch(void* const* d_in, const int* in_sizes, int n_in,
                              void* d_out, int out_size, void* d_ws, size_t ws_size,
                              hipStream_t stream) {
    const int*   tokens = (const int*)  d_in[0];  // [B,T] int32
    const float* E      = (const float*)d_in[1];  // [V,D]
    const float* W      = (const float*)d_in[2];  // [D,H]
    const float* U      = (const float*)d_in[3];  // [H,H]
    const float* bias   = (const float*)d_in[4];  // [H]
    const float* Wd     = (const float*)d_in[5];  // [H,C]
    const float* bd     = (const float*)d_in[6];  // [C]
    float* out = (float*)d_out;                   // [B,C]
    float* EW  = (float*)d_ws;                    // [V,H] scratch: 1.28 MB

    ew_kernel<<<(V_ * H_ + 255) / 256, 256, 0, stream>>>(E, W, bias, EW);
    rnn_kernel<<<B_, H_, 0, stream>>>(tokens, EW, U, Wd, bd, out);
}

// Round 10
// 373.680 us; speedup vs baseline: 1.2052x; 1.2052x over previous
//
#include <hip/hip_runtime.h>

#define B_ 256
#define T_ 1024
#define V_ 5000
#define D_ 100
#define H_ 64
#define C_ 2

typedef float f32x4 __attribute__((ext_vector_type(4)));

#define SCALE_ 2.885390081777927f   // 2*log2(e): exp2(SCALE*x) == e^{2x}

// ---------------------------------------------------------------------------
// Kernel 1: EW[v][h] = 2*log2e*(sum_d E[v][d]*W[d][h] + b[h])   (unchanged)
// ---------------------------------------------------------------------------
__global__ __launch_bounds__(256) void ew_kernel(const float* __restrict__ E,
                                                 const float* __restrict__ W,
                                                 const float* __restrict__ bias,
                                                 float* __restrict__ EW) {
    int idx = blockIdx.x * 256 + threadIdx.x;   // 0 .. V_*H_
    if (idx >= V_ * H_) return;
    int h = idx & (H_ - 1);
    int v = idx >> 6;
    float acc = bias[h];
    const float* Erow = E + v * D_;
    #pragma unroll 4
    for (int d = 0; d < D_; ++d) {
        acc = fmaf(Erow[d], W[d * H_ + h], acc);
    }
    EW[idx] = SCALE_ * acc;
}

// ---------------------------------------------------------------------------
// Kernel 2: RNN. R14: 4-WAVE COOPERATIVE step (one block per batch element).
// Single-wave floor is established: grouped-readlane 587, all-LDS 666,
// DPP 743, hybrid 915 cyc/step -- one wave must serially issue ~128
// broadcast+FMA ops/step. Fix: split the dot product across 4 waves.
//   wave w handles k in [16w,16w+16): 16 readlanes (own-wave h copy) +
//   16 FMAs -> partial -> LDS; raw {lgkmcnt(0); s_barrier} (NOT
//   __syncthreads -- that drains vmcnt(0) and would expose wave-0's EW
//   prefetch every step); each wave reads 4 partials, reduces, tanh,
//   updates its full h copy redundantly (identical FP ops => identical h).
// Parity-double-buffered partials => ONE barrier per step is race-free:
//   write p[par] (after bar t-1) cannot pass reads of p[par] (before it).
// Only wave 0 gathers EW; xw seeds wave-0's partial (saves 3x global
// traffic + one add on the serial chain).
// Critical path ~= 120 (rl+fma) + 50 (write+drain) + 30 (bar) + 80 (reduce
// round-trip) + 50 (tanh tail) ~= 330 cyc vs 587.
// ---------------------------------------------------------------------------
__device__ __forceinline__ float readlane_f(float v, int lane) {
    return __uint_as_float(__builtin_amdgcn_readlane(__float_as_uint(v), lane));
}

__global__ __launch_bounds__(256, 1) void rnn_kernel(const int* __restrict__ tokens,
                                                     const float* __restrict__ EW,
                                                     const float* __restrict__ U,
                                                     const float* __restrict__ Wd,
                                                     const float* __restrict__ bd,
                                                     float* __restrict__ out) {
    const int b   = blockIdx.x;        // batch element
    const int tid = threadIdx.x;       // 0..255
    const int w   = tid >> 6;          // wave 0..3
    const int j   = tid & 63;          // hidden unit
    const int kbase = w << 4;          // this wave's k-range start

    __shared__ int   sh_tok[T_ + 2];        // 4 KB + pad (kills tail guard)
    __shared__ float sh_p[2][4][H_];        // parity x wave x j partials, 2 KB

    // --- (2*log2e)*U rows kbase..kbase+15, col j -> 4 float4 (16 VGPRs) ---
    f32x4 uq[4];
    #pragma unroll
    for (int c = 0; c < 4; ++c) {
        #pragma unroll
        for (int i = 0; i < 4; ++i) {
            uq[c][i] = SCALE_ * U[(kbase + 4 * c + i) * H_ + j];
        }
    }
    // pin all 16 values live in VGPRs (R7-proven multi-operand pattern)
    asm volatile("" : "+v"(uq[0]), "+v"(uq[1]), "+v"(uq[2]), "+v"(uq[3]));

    const int* tok = tokens + b * T_;
    #pragma unroll
    for (int k = 0; k < T_ / 256; ++k) {
        sh_tok[k * 256 + tid] = tok[k * 256 + tid];   // coalesced
    }
    if (tid < 2) sh_tok[T_ + tid] = 0;                // pad
    __syncthreads();                                   // once; ok to drain

    float h = 0.f;
    float pooled = 0.f;

    // 2-step EW prefetch pipeline -- wave 0 only (xw seeds its partial)
    int2 tkA = *(const int2*)&sh_tok[0];
    float xw0 = 0.f, xw1 = 0.f;
    if (w == 0) {
        xw0 = EW[tkA.x * H_ + j];
        xw1 = EW[tkA.y * H_ + j];
    }

    // 8 hazard-free readlanes (distinct SGPRs via 8-op pin) + 8 FMAs
    #define RL_GROUP(g)                                                  \
    {                                                                    \
        float s0 = readlane_f(h, kbase + 8 * (g) + 0);                   \
        float s1 = readlane_f(h, kbase + 8 * (g) + 1);                   \
        float s2 = readlane_f(h, kbase + 8 * (g) + 2);                   \
        float s3 = readlane_f(h, kbase + 8 * (g) + 3);                   \
        float s4 = readlane_f(h, kbase + 8 * (g) + 4);                   \
        float s5 = readlane_f(h, kbase + 8 * (g) + 5);                   \
        float s6 = readlane_f(h, kbase + 8 * (g) + 6);                   \
        float s7 = readlane_f(h, kbase + 8 * (g) + 7);                   \
        asm volatile("" : "+s"(s0), "+s"(s1), "+s"(s2), "+s"(s3),        \
                          "+s"(s4), "+s"(s5), "+s"(s6), "+s"(s7));       \
        a0 = fmaf(s0, uq[2 * (g) + 0][0], a0);                           \
        a1 = fmaf(s1, uq[2 * (g) + 0][1], a1);                           \
        a0 = fmaf(s2, uq[2 * (g) + 0][2], a0);                           \
        a1 = fmaf(s3, uq[2 * (g) + 0][3], a1);                           \
        a0 = fmaf(s4, uq[2 * (g) + 1][0], a0);                           \
        a1 = fmaf(s5, uq[2 * (g) + 1][1], a1);                           \
        a0 = fmaf(s6, uq[2 * (g) + 1][2], a0);                           \
        a1 = fmaf(s7, uq[2 * (g) + 1][3], a1);                           \
    }

    // one cooperative recurrence step (par = partial-buffer parity, 0/1)
    #define RNN_STEP(par, tokv, xwv)                                     \
    {                                                                    \
        float a0 = (xwv), a1 = 0.f;                                      \
        RL_GROUP(0) RL_GROUP(1)                                          \
        sh_p[par][w][j] = a0 + a1;                                       \
        asm volatile("s_waitcnt lgkmcnt(0)\n\ts_barrier" ::: "memory");  \
        float p0 = sh_p[par][0][j];                                      \
        float p1 = sh_p[par][1][j];                                      \
        float p2 = sh_p[par][2][j];                                      \
        float p3 = sh_p[par][3][j];                                      \
        float x2 = (p0 + p1) + (p2 + p3);                                \
        float ef = __builtin_amdgcn_exp2f(x2);                           \
        float r  = __builtin_amdgcn_rcpf(ef + 1.f);                      \
        float hn = fmaf(-2.f, r, 1.f);                                   \
        h = ((tokv) != 0) ? hn : h;                                      \
        pooled += h;                                                     \
    }

    for (int t = 0; t < T_; t += 2) {
        // in-loop pin: any uq spill would force an in-loop reload.
        asm volatile("" :: "v"(uq[0]), "v"(uq[1]), "v"(uq[2]), "v"(uq[3]));

        // prefetch steps t+2, t+3 (wave 0; pad makes tail read EW[0], unused)
        int2 tkB = *(const int2*)&sh_tok[t + 2];
        float xw2 = 0.f, xw3 = 0.f;
        if (w == 0) {
            xw2 = EW[tkB.x * H_ + j];
            xw3 = EW[tkB.y * H_ + j];
        }

        RNN_STEP(0, tkA.x, xw0);
        RNN_STEP(1, tkA.y, xw1);

        tkA = tkB;
        xw0 = xw2;
        xw1 = xw3;
    }
    #undef RNN_STEP
    #undef RL_GROUP

    // ---- epilogue: pooled mean -> dense(2) -> sigmoid (wave 0 only) ----
    if (tid < 64) {
        float p = pooled * (1.0f / (float)T_);
        float v0 = p * Wd[j * C_ + 0];
        float v1 = p * Wd[j * C_ + 1];
        #pragma unroll
        for (int off = 32; off >= 1; off >>= 1) {
            v0 += __shfl_down(v0, off, 64);
            v1 += __shfl_down(v1, off, 64);
        }
        if (j == 0) {
            float l0 = v0 + bd[0];
            float l1 = v1 + bd[1];
            out[b * C_ + 0] = 1.f / (1.f + __expf(-l0));
            out[b * C_ + 1] = 1.f / (1.f + __expf(-l1));
        }
    }
}

// ---------------------------------------------------------------------------
extern "C" void kernel_launch(void* const* d_in, const int* in_sizes, int n_in,
                              void* d_out, int out_size, void* d_ws, size_t ws_size,
                              hipStream_t stream) {
    const int*   tokens = (const int*)  d_in[0];  // [B,T] int32
    const float* E      = (const float*)d_in[1];  // [V,D]
    const float* W      = (const float*)d_in[2];  // [D,H]
    const float* U      = (const float*)d_in[3];  // [H,H]
    const float* bias   = (const float*)d_in[4];  // [H]
    const float* Wd     = (const float*)d_in[5];  // [H,C]
    const float* bd     = (const float*)d_in[6];  // [C]
    float* out = (float*)d_out;                   // [B,C]
    float* EW  = (float*)d_ws;                    // [V,H] scratch: 1.28 MB

    ew_kernel<<<(V_ * H_ + 255) / 256, 256, 0, stream>>>(E, W, bias, EW);
    rnn_kernel<<<B_, 256, 0, stream>>>(tokens, EW, U, Wd, bd, out);
}

// Round 11
// 352.410 us; speedup vs baseline: 1.2779x; 1.0604x over previous
//
#include <hip/hip_runtime.h>

#define B_ 256
#define T_ 1024
#define V_ 5000
#define D_ 100
#define H_ 64
#define C_ 2

typedef float f32x2 __attribute__((ext_vector_type(2)));

#define SCALE_ 2.885390081777927f   // 2*log2(e): exp2(SCALE*x) == e^{2x}

// ---------------------------------------------------------------------------
// Kernel 1: EW[v][h] = 2*log2e*(sum_d E[v][d]*W[d][h] + b[h])   (unchanged)
// ---------------------------------------------------------------------------
__global__ __launch_bounds__(256) void ew_kernel(const float* __restrict__ E,
                                                 const float* __restrict__ W,
                                                 const float* __restrict__ bias,
                                                 float* __restrict__ EW) {
    int idx = blockIdx.x * 256 + threadIdx.x;   // 0 .. V_*H_
    if (idx >= V_ * H_) return;
    int h = idx & (H_ - 1);
    int v = idx >> 6;
    float acc = bias[h];
    const float* Erow = E + v * D_;
    #pragma unroll 4
    for (int d = 0; d < D_; ++d) {
        acc = fmaf(Erow[d], W[d * H_ + h], acc);
    }
    EW[idx] = SCALE_ * acc;
}

// ---------------------------------------------------------------------------
// Kernel 2: RNN, one wave per batch element (R14's 4-wave coop regressed:
// 719 cyc/step -- barrier round-trip > issue saved; reverted to R10 base).
// R15: v_pk_fma_f32 with 64-bit SGPR-PAIR broadcast operands.
//   - 8 readlanes/group land in SGPRs; (u64(hi)<<32)|lo coalesces to a
//     zero-cost REG_SEQUENCE pair build (no SALU in the hot path).
//   - one asm per group issues 4 v_pk_fma_f32, each s[2n:2n+1] * v-pair:
//     64 fma -> 32 pk_fma; per-step VALU ~128 -> ~111 insts.
//   - 4 f32x2 accumulator chains (A,B,C,D): same-chain dep distance 4
//     insts (8 cyc) >= pk_fma latency.
//   - the in-loop asm "v"(uq2[i]) uses ARE the register pin for U.
// Floor data: grouped-rl 587 / all-LDS 666 / DPP 743 / hybrid 915 /
// 4-wave 719 cyc per step. This attacks the only remaining term (issue
// count) without touching the proven-fatal serial-latency structures.
// Kept: padded sh_tok, 2-step EW prefetch, tanh = 1 - 2*rcp(exp2(s*x)+1).
// ---------------------------------------------------------------------------
__global__ __launch_bounds__(64, 1) void rnn_kernel(const int* __restrict__ tokens,
                                                    const float* __restrict__ EW,
                                                    const float* __restrict__ U,
                                                    const float* __restrict__ Wd,
                                                    const float* __restrict__ bd,
                                                    float* __restrict__ out) {
    const int b = blockIdx.x;     // batch element
    const int j = threadIdx.x;    // 0..63 : hidden unit

    __shared__ int sh_tok[T_ + 2];   // 4 KB + pad (kills tail guard)

    // --- (2*log2e)*U column j as 32 adjacent-VGPR pairs (64 VGPRs). ---
    // uq2[i] = ( s*U[2i][j], s*U[2i+1][j] )
    f32x2 uq2[32];
    #pragma unroll
    for (int i = 0; i < 32; ++i) {
        uq2[i][0] = SCALE_ * U[(2 * i + 0) * H_ + j];
        uq2[i][1] = SCALE_ * U[(2 * i + 1) * H_ + j];
    }
    // init pin (two 16-operand groups): all pairs live at once.
    asm volatile("" : "+v"(uq2[0]),  "+v"(uq2[1]),  "+v"(uq2[2]),  "+v"(uq2[3]),
                      "+v"(uq2[4]),  "+v"(uq2[5]),  "+v"(uq2[6]),  "+v"(uq2[7]),
                      "+v"(uq2[8]),  "+v"(uq2[9]),  "+v"(uq2[10]), "+v"(uq2[11]),
                      "+v"(uq2[12]), "+v"(uq2[13]), "+v"(uq2[14]), "+v"(uq2[15]));
    asm volatile("" : "+v"(uq2[16]), "+v"(uq2[17]), "+v"(uq2[18]), "+v"(uq2[19]),
                      "+v"(uq2[20]), "+v"(uq2[21]), "+v"(uq2[22]), "+v"(uq2[23]),
                      "+v"(uq2[24]), "+v"(uq2[25]), "+v"(uq2[26]), "+v"(uq2[27]),
                      "+v"(uq2[28]), "+v"(uq2[29]), "+v"(uq2[30]), "+v"(uq2[31]));

    const int* tok = tokens + b * T_;
    #pragma unroll
    for (int k = 0; k < T_ / H_; ++k) {
        sh_tok[k * H_ + j] = tok[k * H_ + j];    // coalesced
    }
    if (j < 2) sh_tok[T_ + j] = 0;               // pad
    __syncthreads();

    float h = 0.f;
    float pooled = 0.f;

    // 2-step-deep xw prefetch pipeline (covers L2 latency of EW gather)
    int2 tkA = *(const int2*)&sh_tok[0];
    float xw0 = EW[tkA.x * H_ + j];
    float xw1 = EW[tkA.y * H_ + j];

    // group g: k = 8g..8g+7. 8 readlanes -> 4 SGPR pairs -> 4 pk_fma.
    #define DOT_GROUP(g)                                                 \
    {                                                                    \
        unsigned l0 = __builtin_amdgcn_readlane(hb, 8 * (g) + 0);        \
        unsigned l1 = __builtin_amdgcn_readlane(hb, 8 * (g) + 1);        \
        unsigned l2 = __builtin_amdgcn_readlane(hb, 8 * (g) + 2);        \
        unsigned l3 = __builtin_amdgcn_readlane(hb, 8 * (g) + 3);        \
        unsigned l4 = __builtin_amdgcn_readlane(hb, 8 * (g) + 4);        \
        unsigned l5 = __builtin_amdgcn_readlane(hb, 8 * (g) + 5);        \
        unsigned l6 = __builtin_amdgcn_readlane(hb, 8 * (g) + 6);        \
        unsigned l7 = __builtin_amdgcn_readlane(hb, 8 * (g) + 7);        \
        unsigned long long p0 = ((unsigned long long)l1 << 32) | l0;     \
        unsigned long long p1 = ((unsigned long long)l3 << 32) | l2;     \
        unsigned long long p2 = ((unsigned long long)l5 << 32) | l4;     \
        unsigned long long p3 = ((unsigned long long)l7 << 32) | l6;     \
        asm("v_pk_fma_f32 %0, %4, %5, %0\n\t"                            \
            "v_pk_fma_f32 %1, %6, %7, %1\n\t"                            \
            "v_pk_fma_f32 %2, %8, %9, %2\n\t"                            \
            "v_pk_fma_f32 %3, %10, %11, %3"                              \
            : "+v"(accA), "+v"(accB), "+v"(accC), "+v"(accD)             \
            : "s"(p0), "v"(uq2[4 * (g) + 0]),                            \
              "s"(p1), "v"(uq2[4 * (g) + 1]),                            \
              "s"(p2), "v"(uq2[4 * (g) + 2]),                            \
              "s"(p3), "v"(uq2[4 * (g) + 3]));                           \
    }

    // one recurrence step: paired broadcast + packed FMA + clampless tanh
    #define RNN_STEP(tokv, xwv)                                          \
    {                                                                    \
        unsigned hb = __float_as_uint(h);                                \
        f32x2 accA = {(xwv), 0.f};                                       \
        f32x2 accB = {0.f, 0.f};                                         \
        f32x2 accC = {0.f, 0.f};                                         \
        f32x2 accD = {0.f, 0.f};                                         \
        DOT_GROUP(0) DOT_GROUP(1) DOT_GROUP(2) DOT_GROUP(3)              \
        DOT_GROUP(4) DOT_GROUP(5) DOT_GROUP(6) DOT_GROUP(7)              \
        float x2 = ((accA[0] + accA[1]) + (accB[0] + accB[1]))           \
                 + ((accC[0] + accC[1]) + (accD[0] + accD[1]));          \
        float ef = __builtin_amdgcn_exp2f(x2);                           \
        float r  = __builtin_amdgcn_rcpf(ef + 1.f);                      \
        float hn = fmaf(-2.f, r, 1.f);                                   \
        h = ((tokv) != 0) ? hn : h;                                      \
        pooled += h;                                                     \
    }

    for (int t = 0; t < T_; t += 2) {
        // prefetch steps t+2, t+3 (pad makes the tail read safe: EW[0])
        int2 tkB = *(const int2*)&sh_tok[t + 2];
        float xw2 = EW[tkB.x * H_ + j];
        float xw3 = EW[tkB.y * H_ + j];

        RNN_STEP(tkA.x, xw0);
        RNN_STEP(tkA.y, xw1);

        tkA = tkB;
        xw0 = xw2;
        xw1 = xw3;
    }
    #undef RNN_STEP
    #undef DOT_GROUP

    // ---- epilogue: pooled mean -> dense(2) -> sigmoid ----
    float p = pooled * (1.0f / (float)T_);
    float v0 = p * Wd[j * C_ + 0];
    float v1 = p * Wd[j * C_ + 1];
    #pragma unroll
    for (int off = 32; off >= 1; off >>= 1) {
        v0 += __shfl_down(v0, off, 64);
        v1 += __shfl_down(v1, off, 64);
    }
    if (j == 0) {
        float l0 = v0 + bd[0];
        float l1 = v1 + bd[1];
        out[b * C_ + 0] = 1.f / (1.f + __expf(-l0));
        out[b * C_ + 1] = 1.f / (1.f + __expf(-l1));
    }
}

// ---------------------------------------------------------------------------
extern "C" void kernel_launch(void* const* d_in, const int* in_sizes, int n_in,
                              void* d_out, int out_size, void* d_ws, size_t ws_size,
                              hipStream_t stream) {
    const int*   tokens = (const int*)  d_in[0];  // [B,T] int32
    const float* E      = (const float*)d_in[1];  // [V,D]
    const float* W      = (const float*)d_in[2];  // [D,H]
    const float* U      = (const float*)d_in[3];  // [H,H]
    const float* bias   = (const float*)d_in[4];  // [H]
    const float* Wd     = (const float*)d_in[5];  // [H,C]
    const float* bd     = (const float*)d_in[6];  // [C]
    float* out = (float*)d_out;                   // [B,C]
    float* EW  = (float*)d_ws;                    // [V,H] scratch: 1.28 MB

    ew_kernel<<<(V_ * H_ + 255) / 256, 256, 0, stream>>>(E, W, bias, EW);
    rnn_kernel<<<B_, H_, 0, stream>>>(tokens, EW, U, Wd, bd, out);
}

// Round 12
// 318.742 us; speedup vs baseline: 1.4129x; 1.1056x over previous
//
#include <hip/hip_runtime.h>

#define B_ 256
#define T_ 1024
#define V_ 5000
#define D_ 100
#define H_ 64
#define C_ 2

typedef float f32x4 __attribute__((ext_vector_type(4)));

#define SCALE_ 2.885390081777927f   // 2*log2(e): exp2(SCALE*x) == e^{2x}

// ---------------------------------------------------------------------------
// Kernel 1: EW[v][h] = 2*log2e*(sum_d E[v][d]*W[d][h] + b[h])
// ---------------------------------------------------------------------------
__global__ __launch_bounds__(256) void ew_kernel(const float* __restrict__ E,
                                                 const float* __restrict__ W,
                                                 const float* __restrict__ bias,
                                                 float* __restrict__ EW) {
    int idx = blockIdx.x * 256 + threadIdx.x;   // 0 .. V_*H_
    if (idx >= V_ * H_) return;
    int h = idx & (H_ - 1);
    int v = idx >> 6;
    float acc = bias[h];
    const float* Erow = E + v * D_;
    #pragma unroll 4
    for (int d = 0; d < D_; ++d) {
        acc = fmaf(Erow[d], W[d * H_ + h], acc);
    }
    EW[idx] = SCALE_ * acc;
}

// ---------------------------------------------------------------------------
// Kernel 2: RNN, one wave per batch element — R10 (session best: 320.8 us
// total, rnn 252.5 us = 587 cyc/step). REVERT per pre-commitment after R15
// (pk_fma, pin broke: VGPR=48) regressed.
// Structural-floor evidence across 12 variants:
//   grouped-readlane 587 | all-LDS 666 | 4-wave coop 719 | DPP 743 |
//   hybrid VALU+DS 915 cyc/step; NE>1 per wave provably non-winning at
//   B == CU count; barrier cooperation loses to its own round-trip.
// Step floor = 64 readlane (~4cyc eff) + 64 fma + serial tanh tail; the
// h->h dependence chain admits no cheaper broadcast on this hardware.
// Key structures (each HW-verified):
//  - U pinned in 64 VGPRs: "+v" pin over all 16 f32x4 at init AND in-loop
//    (the ONLY pin shape that holds; single-op or input-only pins break)
//  - group-of-8 readlanes into 8 simultaneously-live SGPRs ("+s" 8-op pin)
//    then 8 FMAs: producer->consumer distance >= 8 insts covers the
//    VALU-writes-SGPR hazard; no SGPR recycling WAR
//  - padded sh_tok (no tail guard), 2-step EW prefetch pipeline
//  - clampless tanh: hn = 1 - 2*rcp(exp2(SCALE*x)+1); inf->1, 0->-1
// ---------------------------------------------------------------------------
__device__ __forceinline__ float readlane_f(float v, int lane) {
    return __uint_as_float(__builtin_amdgcn_readlane(__float_as_uint(v), lane));
}

__global__ __launch_bounds__(64, 1) void rnn_kernel(const int* __restrict__ tokens,
                                                    const float* __restrict__ EW,
                                                    const float* __restrict__ U,
                                                    const float* __restrict__ Wd,
                                                    const float* __restrict__ bd,
                                                    float* __restrict__ out) {
    const int b = blockIdx.x;     // batch element
    const int j = threadIdx.x;    // 0..63 : hidden unit

    __shared__ int sh_tok[T_ + 2];   // 4 KB + pad (kills tail guard)

    // --- (2*log2e)*U column j -> 16 float4 (64 VGPRs). Coalesced. ---
    f32x4 uq[16];
    #pragma unroll
    for (int c = 0; c < 16; ++c) {
        uq[c][0] = SCALE_ * U[(4 * c + 0) * H_ + j];
        uq[c][1] = SCALE_ * U[(4 * c + 1) * H_ + j];
        uq[c][2] = SCALE_ * U[(4 * c + 2) * H_ + j];
        uq[c][3] = SCALE_ * U[(4 * c + 3) * H_ + j];
    }
    // SINGLE pin: all 64 values live in VGPRs at once.
    asm volatile("" : "+v"(uq[0]), "+v"(uq[1]), "+v"(uq[2]), "+v"(uq[3]),
                      "+v"(uq[4]), "+v"(uq[5]), "+v"(uq[6]), "+v"(uq[7]),
                      "+v"(uq[8]), "+v"(uq[9]), "+v"(uq[10]), "+v"(uq[11]),
                      "+v"(uq[12]), "+v"(uq[13]), "+v"(uq[14]), "+v"(uq[15]));

    const int* tok = tokens + b * T_;
    #pragma unroll
    for (int k = 0; k < T_ / H_; ++k) {
        sh_tok[k * H_ + j] = tok[k * H_ + j];    // coalesced
    }
    if (j < 2) sh_tok[T_ + j] = 0;               // pad
    __syncthreads();

    float h = 0.f;
    float pooled = 0.f;

    // 2-step-deep xw prefetch pipeline (covers L2 latency of EW gather)
    int2 tkA = *(const int2*)&sh_tok[0];
    float xw0 = EW[tkA.x * H_ + j];
    float xw1 = EW[tkA.y * H_ + j];

    // one group: 8 hazard-free readlanes (distinct SGPRs) then 8 FMAs
    #define DOT_GROUP(g)                                                 \
    {                                                                    \
        float s0 = readlane_f(h, 8 * (g) + 0);                           \
        float s1 = readlane_f(h, 8 * (g) + 1);                           \
        float s2 = readlane_f(h, 8 * (g) + 2);                           \
        float s3 = readlane_f(h, 8 * (g) + 3);                           \
        float s4 = readlane_f(h, 8 * (g) + 4);                           \
        float s5 = readlane_f(h, 8 * (g) + 5);                           \
        float s6 = readlane_f(h, 8 * (g) + 6);                           \
        float s7 = readlane_f(h, 8 * (g) + 7);                           \
        asm volatile("" : "+s"(s0), "+s"(s1), "+s"(s2), "+s"(s3),        \
                          "+s"(s4), "+s"(s5), "+s"(s6), "+s"(s7));       \
        a0 = fmaf(s0, uq[2 * (g) + 0][0], a0);                           \
        a1 = fmaf(s1, uq[2 * (g) + 0][1], a1);                           \
        a2 = fmaf(s2, uq[2 * (g) + 0][2], a2);                           \
        a3 = fmaf(s3, uq[2 * (g) + 0][3], a3);                           \
        a0 = fmaf(s4, uq[2 * (g) + 1][0], a0);                           \
        a1 = fmaf(s5, uq[2 * (g) + 1][1], a1);                           \
        a2 = fmaf(s6, uq[2 * (g) + 1][2], a2);                           \
        a3 = fmaf(s7, uq[2 * (g) + 1][3], a3);                           \
    }

    // one recurrence step: grouped hazard-free broadcast + pinned-reg U
    #define RNN_STEP(tokv, xwv)                                          \
    {                                                                    \
        float a0 = (xwv), a1 = 0.f, a2 = 0.f, a3 = 0.f;                  \
        DOT_GROUP(0) DOT_GROUP(1) DOT_GROUP(2) DOT_GROUP(3)              \
        DOT_GROUP(4) DOT_GROUP(5) DOT_GROUP(6) DOT_GROUP(7)              \
        float x2 = (a0 + a1) + (a2 + a3);                                \
        float ef = __builtin_amdgcn_exp2f(x2);                           \
        float r = __builtin_amdgcn_rcpf(ef + 1.f);                       \
        float hn = fmaf(-2.f, r, 1.f);                                   \
        h = ((tokv) != 0) ? hn : h;                                      \
        pooled += h;                                                     \
    }

    for (int t = 0; t < T_; t += 2) {
        // in-loop pin: any uq spill would force an in-loop reload.
        asm volatile("" :: "v"(uq[0]), "v"(uq[1]), "v"(uq[2]), "v"(uq[3]),
                           "v"(uq[4]), "v"(uq[5]), "v"(uq[6]), "v"(uq[7]),
                           "v"(uq[8]), "v"(uq[9]), "v"(uq[10]), "v"(uq[11]),
                           "v"(uq[12]), "v"(uq[13]), "v"(uq[14]), "v"(uq[15]));

        // prefetch steps t+2, t+3 (pad makes the tail read safe: EW[0])
        int2 tkB = *(const int2*)&sh_tok[t + 2];
        float xw2 = EW[tkB.x * H_ + j];
        float xw3 = EW[tkB.y * H_ + j];

        RNN_STEP(tkA.x, xw0);
        RNN_STEP(tkA.y, xw1);

        tkA = tkB;
        xw0 = xw2;
        xw1 = xw3;
    }
    #undef RNN_STEP
    #undef DOT_GROUP

    // ---- epilogue: pooled mean -> dense(2) -> sigmoid ----
    float p = pooled * (1.0f / (float)T_);
    float v0 = p * Wd[j * C_ + 0];
    float v1 = p * Wd[j * C_ + 1];
    #pragma unroll
    for (int off = 32; off >= 1; off >>= 1) {
        v0 += __shfl_down(v0, off, 64);
        v1 += __shfl_down(v1, off, 64);
    }
    if (j == 0) {
        float l0 = v0 + bd[0];
        float l1 = v1 + bd[1];
        out[b * C_ + 0] = 1.f / (1.f + __expf(-l0));
        out[b * C_ + 1] = 1.f / (1.f + __expf(-l1));
    }
}

// ---------------------------------------------------------------------------
extern "C" void kernel_launch(void* const* d_in, const int* in_sizes, int n_in,
                              void* d_out, int out_size, void* d_ws, size_t ws_size,
                              hipStream_t stream) {
    const int*   tokens = (const int*)  d_in[0];  // [B,T] int32
    const float* E      = (const float*)d_in[1];  // [V,D]
    const float* W      = (const float*)d_in[2];  // [D,H]
    const float* U      = (const float*)d_in[3];  // [H,H]
    const float* bias   = (const float*)d_in[4];  // [H]
    const float* Wd     = (const float*)d_in[5];  // [H,C]
    const float* bd     = (const float*)d_in[6];  // [C]
    float* out = (float*)d_out;                   // [B,C]
    float* EW  = (float*)d_ws;                    // [V,H] scratch: 1.28 MB

    ew_kernel<<<(V_ * H_ + 255) / 256, 256, 0, stream>>>(E, W, bias, EW);
    rnn_kernel<<<B_, H_, 0, stream>>>(tokens, EW, U, Wd, bd, out);
}